// Round 10
// baseline (283.904 us; speedup 1.0000x reference)
//
#include <hip/hip_runtime.h>
#include <stdint.h>

// KmeansAudioQuantizer on MI355X (gfx950)
// B=8, L=1024, C=1024, N=5000.  M = B*L = 8192 queries.
//
// Round 10: faithful m201-style 8-phase schedule (2 K-tiles per iteration) on
// the 256x256 geometry. Swizzle (R9-verified: bank conflicts 2.36e7 -> 1028)
// and block-local epilogue (R5/R8/R9-verified absmax 0.0) unchanged.
//   - per phase: {ds_read subtile | stage 1 unit (2 gload_lds) | barrier |
//     lgkmcnt(0) | setprio(1) | 16 MFMA | setprio(0) | [vmcnt @ph4/ph8] | barrier}
//   - units consumption-aligned: A-unit h = rows {h*64..h*64+63, 128+h*64..}
//     (both wm panels), B-unit h = rows {wn*64+h*32..+31, wn=0..3}
//   - counted waits: vmcnt(6) end-ph4, vmcnt(8) end-ph8; prologue vmcnt(8);
//     peel degrades 0. Never drain-to-0 in steady state.
//   - stagger: unit staged at the phase AFTER its last ds_read; per-phase
//     lgkmcnt(0)+barrier makes cross-wave overwrite safe.

#define M_TOTAL  8192
#define K_DIM    1024
#define N_REAL   5000
#define N_PAD    5120
#define NB_CNT   20          // N_PAD / 256
#define SLOTS    6           // slot0 = slice min, slots 1..5 = margin candidates
#define MARGIN   8.0f

typedef __attribute__((ext_vector_type(8))) short bf16x8;
typedef __attribute__((ext_vector_type(4))) float f32x4;
typedef unsigned long long u64;

__device__ __forceinline__ ushort f2bf(float x) {
  union { float f; uint32_t u; } v; v.f = x;
  uint32_t r = v.u + 0x7FFFu + ((v.u >> 16) & 1u);   // round-to-nearest-even
  return (ushort)(r >> 16);
}

__device__ __forceinline__ void async16(void* lds, const void* g) {
  __builtin_amdgcn_global_load_lds(
      (const __attribute__((address_space(1))) void*)g,
      (__attribute__((address_space(3))) void*)lds, 16, 0, 0);
}

// monotone float<->uint32 encode (total order matches float order)
__device__ __forceinline__ uint32_t fenc(float f) {
  union { float f; uint32_t u; } v; v.f = f;
  return v.u ^ ((v.u >> 31) ? 0xFFFFFFFFu : 0x80000000u);
}
__device__ __forceinline__ float fdec(uint32_t e) {
  uint32_t u = e ^ ((e & 0x80000000u) ? 0x80000000u : 0xFFFFFFFFu);
  union { uint32_t u; float f; } v; v.u = u; return v.f;
}

#define MFMA16(a, b, c) __builtin_amdgcn_mfma_f32_16x16x32_bf16((a), (b), (c), 0, 0, 0)

// ---------------------------------------------------------------- prep kernels

__global__ __launch_bounds__(256) void convert_z(const float4* __restrict__ z4,
                                                 ushort* __restrict__ zb, int n4) {
  int i = blockIdx.x * blockDim.x + threadIdx.x;
  int stride = gridDim.x * blockDim.x;
  for (; i < n4; i += stride) {
    float4 v = z4[i];
    ushort4 u;
    u.x = f2bf(v.x); u.y = f2bf(v.y); u.z = f2bf(v.z); u.w = f2bf(v.w);
    *(ushort4*)&zb[(size_t)i * 4] = u;
  }
}

__global__ __launch_bounds__(256) void prep_cb(const float* __restrict__ cb,
                                               ushort* __restrict__ cbb,
                                               float* __restrict__ c2) {
  __shared__ float sred[4];
  const int row = blockIdx.x;       // 0..5119
  const int tid = threadIdx.x;
  if (row >= N_REAL) {              // zero pad rows so GEMM reads are benign
    ushort4 zz; zz.x = zz.y = zz.z = zz.w = 0;
    *(ushort4*)&cbb[(size_t)row * K_DIM + tid * 4] = zz;
    if (tid == 0) c2[row] = 0.f;
    return;
  }
  float4 v = ((const float4*)(cb + (size_t)row * K_DIM))[tid];
  ushort4 u;
  u.x = f2bf(v.x); u.y = f2bf(v.y); u.z = f2bf(v.z); u.w = f2bf(v.w);
  *(ushort4*)&cbb[(size_t)row * K_DIM + tid * 4] = u;
  float s = v.x * v.x + v.y * v.y + v.z * v.z + v.w * v.w;
  #pragma unroll
  for (int off = 32; off; off >>= 1) s += __shfl_down(s, off);
  int wv = tid >> 6, ln = tid & 63;
  if (ln == 0) sred[wv] = s;
  __syncthreads();
  if (tid == 0) c2[row] = sred[0] + sred[1] + sred[2] + sred[3];
}

// ------------------------------------------------- GEMM + fused argmin/collect
// 256x256 tile, BK=64, 8 waves (2x4 of 128x64), 16x16x32 bf16 MFMA.
// LDS per buffer d (65536 B): A at +0 as [half h][panel wm][64 rows][128 B],
// B at +32768 as [half h][panel wn(4)][32 rows][128 B].
// Swizzle: byte-in-row ^= ((local_row & 7) << 4), both staged-source and read.

__global__ __launch_bounds__(512, 2) void gemm_score(const ushort* __restrict__ A,
                                                     const ushort* __restrict__ Bm,
                                                     const float* __restrict__ c2,
                                                     u64* __restrict__ cand) {
  __shared__ __align__(16) char smem[131072];

  const int tid  = threadIdx.x;
  const int wave = tid >> 6, lane = tid & 63;
  const int wm = wave >> 2, wn = wave & 3;     // 2 x 4 wave grid
  const int tM = blockIdx.y * 256;
  const int tN = blockIdx.x * 256;
  const int nb = blockIdx.x;

  f32x4 acc[8][4];
  #pragma unroll
  for (int i = 0; i < 8; ++i)
    #pragma unroll
    for (int j = 0; j < 4; ++j)
      acc[i][j] = (f32x4)0.f;

  // staging: linear LDS dest (tid*16 per 8KB issue), inverse-swizzled source
  const int sr   = tid >> 3;                   // 0..63
  const int sc   = ((tid & 7) ^ (sr & 7)) * 8; // source element offset in row
  const int sdst = tid * 16;
  const int pn   = tid >> 8;                   // 0/1: which wn-panel pair (B)
  const int blr  = sr & 31;                    // B local row

  auto stA = [&](int d, int h, int k0) {
    char* dst = smem + d * 65536 + h * 16384;
    async16(dst + sdst,
            (const char*)A + ((size_t)(tM + h * 64 + sr) * K_DIM + k0 + sc) * 2);
    async16(dst + 8192 + sdst,
            (const char*)A + ((size_t)(tM + 128 + h * 64 + sr) * K_DIM + k0 + sc) * 2);
  };
  auto stB = [&](int d, int h, int k0) {
    char* dst = smem + d * 65536 + 32768 + h * 16384;
    async16(dst + sdst,
            (const char*)Bm + ((size_t)(tN + pn * 64 + h * 32 + blr) * K_DIM + k0 + sc) * 2);
    async16(dst + 8192 + sdst,
            (const char*)Bm + ((size_t)(tN + (pn + 2) * 64 + h * 32 + blr) * K_DIM + k0 + sc) * 2);
  };

  // swizzled ds_read_b128
  const int lrow = lane & 15;
  const int kgb  = (lane >> 4) * 16;
  const int xorv = (lane & 7) << 4;
  auto ldA8 = [&](int d, int h, int i, int kk) {
    return *(const bf16x8*)(smem + d * 65536 + h * 16384 + wm * 8192
                            + (i * 16 + lrow) * 128 + ((kk * 64 + kgb) ^ xorv));
  };
  auto ldB8 = [&](int d, int h, int jj, int kk) {
    return *(const bf16x8*)(smem + d * 65536 + 32768 + h * 16384 + wn * 4096
                            + (jj * 16 + lrow) * 128 + ((kk * 64 + kgb) ^ xorv));
  };

  bf16x8 ar[4][2], brL[2][2], brH[2][2];
  auto rdA = [&](int d, int h) {
    #pragma unroll
    for (int i = 0; i < 4; ++i) { ar[i][0] = ldA8(d, h, i, 0); ar[i][1] = ldA8(d, h, i, 1); }
  };
  auto rdBL = [&](int d) {
    #pragma unroll
    for (int j = 0; j < 2; ++j) { brL[j][0] = ldB8(d, 0, j, 0); brL[j][1] = ldB8(d, 0, j, 1); }
  };
  auto rdBH = [&](int d) {
    #pragma unroll
    for (int j = 0; j < 2; ++j) { brH[j][0] = ldB8(d, 1, j, 0); brH[j][1] = ldB8(d, 1, j, 1); }
  };
  auto MMqL = [&](int hA) {       // quadrant (hA, B-lo): 16 MFMA
    #pragma unroll
    for (int i = 0; i < 4; ++i)
      #pragma unroll
      for (int j = 0; j < 2; ++j) {
        acc[hA*4+i][j] = MFMA16(ar[i][0], brL[j][0], acc[hA*4+i][j]);
        acc[hA*4+i][j] = MFMA16(ar[i][1], brL[j][1], acc[hA*4+i][j]);
      }
  };
  auto MMqH = [&](int hA) {       // quadrant (hA, B-hi): 16 MFMA
    #pragma unroll
    for (int i = 0; i < 4; ++i)
      #pragma unroll
      for (int j = 0; j < 2; ++j) {
        acc[hA*4+i][2+j] = MFMA16(ar[i][0], brH[j][0], acc[hA*4+i][2+j]);
        acc[hA*4+i][2+j] = MFMA16(ar[i][1], brH[j][1], acc[hA*4+i][2+j]);
      }
  };

#define BAR()    __builtin_amdgcn_s_barrier()
#define LGKM0()  asm volatile("s_waitcnt lgkmcnt(0)" ::: "memory")
#define PRIO1()  __builtin_amdgcn_s_setprio(1)
#define PRIO0()  __builtin_amdgcn_s_setprio(0)

  // prologue: stage tiles 0 (buf0) and 1 (buf1), slot order s1..s8
  stA(0,0,0);  stB(0,1,0);  stB(0,0,0);  stA(0,1,0);
  stA(1,0,64); stB(1,1,64); stB(1,0,64); stA(1,1,64);
  asm volatile("s_waitcnt vmcnt(8)" ::: "memory");   // T0 units landed
  BAR();

  #pragma unroll 1
  for (int it = 0; it < 7; ++it) {
    const int kA = (2*it + 2) * 64;   // stages for tile 2it+2 -> buf0
    const int kB = (2*it + 3) * 64;   // stages for tile 2it+3 -> buf1
    // ph1: buf0 quad (aLo,bLo); no stage
    rdA(0,0); rdBL(0);
    BAR(); LGKM0(); PRIO1(); MMqL(0); PRIO0(); BAR();
    // ph2: bHi; stage s1 = T+2 A-lo (buf0 Alo last read ph1)
    rdBH(0); stA(0,0,kA);
    BAR(); LGKM0(); PRIO1(); MMqH(0); PRIO0(); BAR();
    // ph3: aHi + re-read bLo; stage s2 = T+2 B-hi (last read ph2)
    rdA(0,1); rdBL(0); stB(0,1,kA);
    BAR(); LGKM0(); PRIO1(); MMqL(1); PRIO0(); BAR();
    // ph4: regs only; stage s3 = T+2 B-lo (last read ph3); end: vmcnt(6)
    stB(0,0,kA);
    BAR(); LGKM0(); PRIO1(); MMqH(1); PRIO0();
    asm volatile("s_waitcnt vmcnt(6)" ::: "memory");  // buf1 units landed
    BAR();
    // ph5: buf1 quad (aLo,bLo); stage s4 = T+2 A-hi (last read ph3)
    rdA(1,0); rdBL(1); stA(0,1,kA);
    BAR(); LGKM0(); PRIO1(); MMqL(0); PRIO0(); BAR();
    // ph6: bHi; stage s5 = T+3 A-lo (buf1 Alo last read ph5)
    rdBH(1); stA(1,0,kB);
    BAR(); LGKM0(); PRIO1(); MMqH(0); PRIO0(); BAR();
    // ph7: aHi + re-read bLo; stage s6 = T+3 B-hi (last read ph6)
    rdA(1,1); rdBL(1); stB(1,1,kB);
    BAR(); LGKM0(); PRIO1(); MMqL(1); PRIO0(); BAR();
    // ph8: regs only; stage s7,s8 = T+3 B-lo, A-hi (last read ph7); vmcnt(8)
    stB(1,0,kB); stA(1,1,kB);
    BAR(); LGKM0(); PRIO1(); MMqH(1); PRIO0();
    asm volatile("s_waitcnt vmcnt(8)" ::: "memory");  // next buf0 units landed
    BAR();
  }

  // peeled final pair: tiles 14 (buf0), 15 (buf1); no staging
  rdA(0,0); rdBL(0);
  BAR(); LGKM0(); PRIO1(); MMqL(0); PRIO0(); BAR();
  rdBH(0);
  BAR(); LGKM0(); PRIO1(); MMqH(0); PRIO0(); BAR();
  rdA(0,1); rdBL(0);
  BAR(); LGKM0(); PRIO1(); MMqL(1); PRIO0(); BAR();
  BAR(); LGKM0(); PRIO1(); MMqH(1); PRIO0();
  asm volatile("s_waitcnt vmcnt(0)" ::: "memory");    // tile-15 units landed
  BAR();
  rdA(1,0); rdBL(1);
  BAR(); LGKM0(); PRIO1(); MMqL(0); PRIO0(); BAR();
  rdBH(1);
  BAR(); LGKM0(); PRIO1(); MMqH(0); PRIO0(); BAR();
  rdA(1,1); rdBL(1);
  BAR(); LGKM0(); PRIO1(); MMqL(1); PRIO0(); BAR();
  PRIO1(); MMqH(1); PRIO0();

  // ---- fused epilogue: block-local, LDS atomics only (unchanged from R8/R9)
  // C/D layout: row = I*16 + (lane>>4)*4 + r (in wave tile), col = J*16 + (lane&15)
  __syncthreads();                             // full drain; reuse LDS
  u64 (*scand)[SLOTS] = (u64 (*)[SLOTS])smem;  // 256*6*8 = 12288 B
  int* scnt = (int*)(smem + 12288);            // 1024 B
  if (tid < 256) {
    scnt[tid] = 0;
    #pragma unroll
    for (int s = 0; s < SLOTS; ++s) scand[tid][s] = ~0ull;
  }
  __syncthreads();

  const int cl = lane & 15, rg = lane >> 4;
  int   ncol[4];
  float c2v[4];
  #pragma unroll
  for (int j = 0; j < 4; ++j) {
    ncol[j] = tN + wn * 64 + j * 16 + cl;
    c2v[j]  = (ncol[j] < N_REAL) ? c2[ncol[j]] : 0.f;
  }

  // pass A: per-row lex-min over this wave's 64 cols -> LDS atomicMin (slot 0)
  #pragma unroll
  for (int i = 0; i < 8; ++i) {
    #pragma unroll
    for (int r = 0; r < 4; ++r) {
      float bv = 3.4e38f; int bc = 0x7fffffff;
      #pragma unroll
      for (int j = 0; j < 4; ++j) {
        float sc2 = (ncol[j] < N_REAL) ? (c2v[j] - 2.0f * acc[i][j][r]) : 3.4e38f;
        if (sc2 < bv || (sc2 == bv && ncol[j] < bc)) { bv = sc2; bc = ncol[j]; }
      }
      #pragma unroll
      for (int off = 1; off < 16; off <<= 1) {   // stays within the rg group
        float ov = __shfl_xor(bv, off);
        int   oc = __shfl_xor(bc, off);
        if (ov < bv || (ov == bv && oc < bc)) { bv = ov; bc = oc; }
      }
      if (cl == 0) {
        const int lr = wm * 128 + i * 16 + rg * 4 + r;
        u64 pk = ((u64)fenc(bv) << 32) | (uint32_t)bc;
        atomicMin(&scand[lr][0], pk);
      }
    }
  }
  __syncthreads();

  // pass B: append margin candidates (excluding the slice-min col)
  #pragma unroll
  for (int i = 0; i < 8; ++i) {
    #pragma unroll
    for (int r = 0; r < 4; ++r) {
      const int lr = wm * 128 + i * 16 + rg * 4 + r;
      const u64 mn = scand[lr][0];
      const float thr  = fdec((uint32_t)(mn >> 32)) + MARGIN;
      const int mincol = (int)(mn & 0xFFFFFFFFu);
      #pragma unroll
      for (int j = 0; j < 4; ++j) {
        if (ncol[j] < N_REAL) {
          float sc2 = c2v[j] - 2.0f * acc[i][j][r];
          if (sc2 <= thr && ncol[j] != mincol) {
            int p = atomicAdd(&scnt[lr], 1);
            if (p < SLOTS - 1)
              scand[lr][1 + p] = ((u64)fenc(sc2) << 32) | (uint32_t)ncol[j];
          }
        }
      }
    }
  }
  __syncthreads();

  // store out: 6 slots per (row, slice); empty slots decode to NaN -> filtered
  if (tid < 256) {
    const size_t base = ((size_t)(tM + tid) * NB_CNT + nb) * SLOTS;
    #pragma unroll
    for (int s = 0; s < SLOTS; ++s) cand[base + s] = scand[tid][s];
  }
}

// ------------------------------------------------------- finalize (per query)

__global__ __launch_bounds__(256) void finalize(const u64* __restrict__ cand,
                                                const float* __restrict__ z,
                                                const float* __restrict__ cb,
                                                const int* __restrict__ mask,
                                                float* __restrict__ out_q,
                                                float* __restrict__ out_i,
                                                float* __restrict__ out_loss) {
  __shared__ u64 swm[4];
  __shared__ float sthr;
  __shared__ int scols[64];
  __shared__ int scnt2;
  __shared__ double sdv[4];
  __shared__ double sbestd;
  __shared__ int    sbesti;

  const int tid = threadIdx.x;
  const int m   = blockIdx.x;
  const int wv = tid >> 6, ln = tid & 63;
  const u64* row = cand + (size_t)m * (NB_CNT * SLOTS);   // 120 entries

  const u64 e = (tid < NB_CNT * SLOTS) ? row[tid] : ~0ull;

  // gmin over slot-0 entries (u64 lex order == (score, col) order)
  u64 g = (tid < NB_CNT * SLOTS && (tid % SLOTS) == 0) ? e : ~0ull;
  #pragma unroll
  for (int off = 32; off; off >>= 1) {
    u64 o = __shfl_down(g, off);
    if (o < g) g = o;
  }
  if (ln == 0) swm[wv] = g;
  __syncthreads();
  if (tid == 0) {
    u64 gg = swm[0];
    for (int w = 1; w < 4; ++w) if (swm[w] < gg) gg = swm[w];
    sthr = fdec((uint32_t)(gg >> 32)) + MARGIN;
    scnt2 = 0;
  }
  __syncthreads();

  // survivors: entries within gmin+MARGIN (empty slots decode NaN -> false)
  if (tid < NB_CNT * SLOTS) {
    float sc = fdec((uint32_t)(e >> 32));
    if (sc <= sthr) {
      int p = atomicAdd(&scnt2, 1);
      if (p < 64) scols[p] = (int)(e & 0xFFFFFFFFu);
    }
  }
  __syncthreads();
  int nc = scnt2 < 64 ? scnt2 : 64;

  // exact f64 rescore: sum c*(c - 2z)
  if (tid == 0) { sbestd = 1e300; sbesti = 0x7fffffff; }
  __syncthreads();
  const float4 zv = ((const float4*)(z + (size_t)m * K_DIM))[tid];
  for (int c = 0; c < nc; ++c) {
    const int n = scols[c];
    float4 cv = ((const float4*)(cb + (size_t)n * K_DIM))[tid];
    double lsum = (double)cv.x * ((double)cv.x - 2.0 * (double)zv.x)
                + (double)cv.y * ((double)cv.y - 2.0 * (double)zv.y)
                + (double)cv.z * ((double)cv.z - 2.0 * (double)zv.z)
                + (double)cv.w * ((double)cv.w - 2.0 * (double)zv.w);
    #pragma unroll
    for (int off = 32; off; off >>= 1) lsum += __shfl_down(lsum, off);
    if (ln == 0) sdv[wv] = lsum;
    __syncthreads();
    if (tid == 0) {
      double s = sdv[0] + sdv[1] + sdv[2] + sdv[3];
      if (s < sbestd || (s == sbestd && n < sbesti)) { sbestd = s; sbesti = n; }
    }
    __syncthreads();
  }

  const int bidx = sbesti;
  if (tid == 0) out_i[m] = (float)bidx;
  const int mk = mask[m];
  float4 qz; qz.x = qz.y = qz.z = qz.w = 0.f;
  float4 src = ((const float4*)(cb + (size_t)bidx * K_DIM))[tid];
  ((float4*)(out_q + (size_t)m * K_DIM))[tid] = mk ? src : qz;
  if (m == 0 && tid == 0) *out_loss = 0.0f;
}

// -------------------------------------------------------------------- launcher

extern "C" void kernel_launch(void* const* d_in, const int* in_sizes, int n_in,
                              void* d_out, int out_size, void* d_ws, size_t ws_size,
                              hipStream_t stream) {
  const float* z    = (const float*)d_in[0];
  const int*   mask = (const int*)d_in[1];
  const float* cb   = (const float*)d_in[2];

  float* out      = (float*)d_out;
  float* out_q    = out;                                   // [8192][1024]
  float* out_i    = out + (size_t)M_TOTAL * K_DIM;         // [8192] (as float)
  float* out_loss = out_i + M_TOTAL;                       // [1]

  char* ws = (char*)d_ws;
  ushort* zb   = (ushort*)(ws);                            // 16,777,216 B
  ushort* cbb  = (ushort*)(ws + 16777216);                 // 10,485,760 B
  float*  c2   = (float*)(ws + 27262976);                  //     20,480 B
  u64*    cand = (u64*)(ws + 27283456);                    //  7,864,320 B  (total 35.1 MB)

  convert_z<<<2048, 256, 0, stream>>>((const float4*)z, zb, (M_TOTAL * K_DIM) / 4);
  prep_cb<<<N_PAD, 256, 0, stream>>>(cb, cbb, c2);

  dim3 g(N_PAD / 256, M_TOTAL / 256);
  gemm_score<<<g, 512, 0, stream>>>(zb, cbb, c2, cand);
  finalize<<<M_TOTAL, 256, 0, stream>>>(cand, z, cb, mask, out_q, out_i, out_loss);
}